// Round 1
// baseline (643.752 us; speedup 1.0000x reference)
//
#include <hip/hip_runtime.h>

#define DIM 128
#define TM 64

// ---------- setup kernels ----------

__global__ void zero_ints(int* __restrict__ p, int n) {
    int i = blockIdx.x * blockDim.x + threadIdx.x;
    if (i < n) p[i] = 0;
}

__global__ void count_kernel(const int* __restrict__ dst, int* __restrict__ counts, int E) {
    int e = blockIdx.x * blockDim.x + threadIdx.x;
    if (e < E) atomicAdd(&counts[dst[e]], 1);
}

// single-block exclusive scan over counts -> row_ptr[0..n], row_ptr[n] = total
__global__ void scan_kernel(const int* __restrict__ counts, int* __restrict__ row_ptr, int n) {
    __shared__ int sums[1024];
    int tid = threadIdx.x;
    int chunk = (n + 1023) >> 10;
    int start = tid * chunk;
    int end = min(start + chunk, n);
    int s = 0;
    for (int i = start; i < end; ++i) s += counts[i];
    sums[tid] = s;
    __syncthreads();
    for (int off = 1; off < 1024; off <<= 1) {
        int v = (tid >= off) ? sums[tid - off] : 0;
        __syncthreads();
        sums[tid] += v;
        __syncthreads();
    }
    int excl = (tid == 0) ? 0 : sums[tid - 1];
    for (int i = start; i < end; ++i) {
        row_ptr[i] = excl;
        excl += counts[i];
    }
    if (tid == 1023) row_ptr[n] = sums[1023];
}

__global__ void invdeg_kernel(const int* __restrict__ counts, float* __restrict__ inv_deg, int n) {
    int v = blockIdx.x * blockDim.x + threadIdx.x;
    if (v < n) {
        int c = counts[v];
        inv_deg[v] = 1.0f / (float)(c > 0 ? c : 1);
    }
}

__global__ void fill_csr(const int* __restrict__ src, const int* __restrict__ dst,
                         const int* __restrict__ row_ptr, int* __restrict__ fill,
                         int* __restrict__ col_idx, int E) {
    int e = blockIdx.x * blockDim.x + threadIdx.x;
    if (e < E) {
        int v = dst[e];
        int pos = row_ptr[v] + atomicAdd(&fill[v], 1);
        col_idx[pos] = src[e];
    }
}

// ---------- aggregation: agg[v] = inv_deg[v] * sum_{u in N(v)} h[u] ----------
// one 32-lane group per node, float4 per lane -> 512B coalesced row reads
__global__ void aggregate_kernel(const float* __restrict__ h, const int* __restrict__ row_ptr,
                                 const int* __restrict__ col_idx, const float* __restrict__ inv_deg,
                                 float* __restrict__ agg, int n) {
    int node = blockIdx.x * (blockDim.x >> 5) + (threadIdx.x >> 5);
    if (node >= n) return;
    int f = (threadIdx.x & 31) << 2;
    int b = row_ptr[node], e = row_ptr[node + 1];
    float ax = 0.f, ay = 0.f, az = 0.f, aw = 0.f;
    for (int i = b; i < e; ++i) {
        int u = col_idx[i];
        const float4 v = *(const float4*)(h + (size_t)u * DIM + f);
        ax += v.x; ay += v.y; az += v.z; aw += v.w;
    }
    float s = inv_deg[node];
    float4 o = make_float4(ax * s, ay * s, az * s, aw * s);
    *(float4*)(agg + (size_t)node * DIM + f) = o;
}

// ---------- fused dual GEMM: h_out = [relu](h_in @ Ws + agg @ Wn + b) ----------
// TM=64 rows per 256-thread block, thread = 4 rows x 8 cols.
// A-tiles stored k-major (transposed) in LDS with XOR swizzle, LDA=64 -> exactly 64KB.
__device__ __forceinline__ int swz(int k, int r) {
    return (k << 6) + ((r ^ ((k & 15) << 2)) & 63);
}

__global__ __launch_bounds__(256, 2) void sage_gemm(
    const float* __restrict__ h_in, const float* __restrict__ agg,
    const float* __restrict__ Ws, const float* __restrict__ Wn,
    const float* __restrict__ bias, float* __restrict__ h_out,
    int n, int do_relu)
{
    __shared__ float hTs[DIM * 64];
    __shared__ float hTn[DIM * 64];
    const int tid = threadIdx.x;
    const int row0 = blockIdx.x * TM;

    // staging: lane k loads columns k of 4 rows, writes one b128 to hT[k][r..r+3]
    {
        const int k = tid & 127;
        const int rb = (tid >> 7) << 2;  // 0 or 4
        #pragma unroll
        for (int pass = 0; pass < 8; ++pass) {
            const int r = pass * 8 + rb;
            float4 vs, vn;
            float* ps = &vs.x;
            float* pn = &vn.x;
            #pragma unroll
            for (int i = 0; i < 4; ++i) {
                const int gr = row0 + r + i;
                if (gr < n) {
                    ps[i] = h_in[(size_t)gr * DIM + k];
                    pn[i] = agg[(size_t)gr * DIM + k];
                } else {
                    ps[i] = 0.f; pn[i] = 0.f;
                }
            }
            *(float4*)&hTs[swz(k, r)] = vs;
            *(float4*)&hTn[swz(k, r)] = vn;
        }
    }
    __syncthreads();

    const int tc = tid & 15;
    const int tr = tid >> 4;
    const int c0 = tc * 8;
    const int r0 = tr * 4;

    float acc[4][8];
    #pragma unroll
    for (int i = 0; i < 4; ++i)
        #pragma unroll
        for (int j = 0; j < 8; ++j) acc[i][j] = 0.f;

    #pragma unroll 4
    for (int k = 0; k < DIM; ++k) {
        const float4 as = *(const float4*)&hTs[swz(k, r0)];
        const float4 an = *(const float4*)&hTn[swz(k, r0)];
        const float4 w0 = *(const float4*)&Ws[k * DIM + c0];
        const float4 w1 = *(const float4*)&Ws[k * DIM + c0 + 4];
        const float4 u0 = *(const float4*)&Wn[k * DIM + c0];
        const float4 u1 = *(const float4*)&Wn[k * DIM + c0 + 4];
        const float a_s[4] = {as.x, as.y, as.z, as.w};
        const float a_n[4] = {an.x, an.y, an.z, an.w};
        const float ws8[8] = {w0.x, w0.y, w0.z, w0.w, w1.x, w1.y, w1.z, w1.w};
        const float wn8[8] = {u0.x, u0.y, u0.z, u0.w, u1.x, u1.y, u1.z, u1.w};
        #pragma unroll
        for (int i = 0; i < 4; ++i)
            #pragma unroll
            for (int j = 0; j < 8; ++j)
                acc[i][j] += a_s[i] * ws8[j] + a_n[i] * wn8[j];
    }

    const float4 b0 = *(const float4*)&bias[c0];
    const float4 b1 = *(const float4*)&bias[c0 + 4];
    const float bb[8] = {b0.x, b0.y, b0.z, b0.w, b1.x, b1.y, b1.z, b1.w};
    #pragma unroll
    for (int i = 0; i < 4; ++i) {
        const int gr = row0 + r0 + i;
        if (gr >= n) continue;
        float o[8];
        #pragma unroll
        for (int j = 0; j < 8; ++j) {
            float v = acc[i][j] + bb[j];
            if (do_relu) v = fmaxf(v, 0.f);
            o[j] = v;
        }
        *(float4*)&h_out[(size_t)gr * DIM + c0]     = make_float4(o[0], o[1], o[2], o[3]);
        *(float4*)&h_out[(size_t)gr * DIM + c0 + 4] = make_float4(o[4], o[5], o[6], o[7]);
    }
}

// ---------- launch ----------

extern "C" void kernel_launch(void* const* d_in, const int* in_sizes, int n_in,
                              void* d_out, int out_size, void* d_ws, size_t ws_size,
                              hipStream_t stream) {
    const float* x      = (const float*)d_in[0];
    const int*   src    = (const int*)d_in[1];
    const int*   dst    = (const int*)d_in[2];
    const float* W_self = (const float*)d_in[3];
    const float* W_neigh= (const float*)d_in[4];
    const float* bias   = (const float*)d_in[5];
    float* out = (float*)d_out;

    const int n = in_sizes[0] / DIM;   // 50000
    const int e = in_sizes[1];         // 800000

    char* ws = (char*)d_ws;
    size_t off = 0;
    auto alloc = [&](size_t bytes) -> void* {
        void* p = ws + off;
        off += (bytes + 255) & ~(size_t)255;
        return p;
    };
    int*   counts  = (int*)alloc((size_t)n * 4);
    int*   fill    = (int*)alloc((size_t)n * 4);
    int*   row_ptr = (int*)alloc((size_t)(n + 1) * 4);
    int*   col_idx = (int*)alloc((size_t)e * 4);
    float* inv_deg = (float*)alloc((size_t)n * 4);
    float* h_a     = (float*)alloc((size_t)n * DIM * 4);
    float* h_b     = (float*)alloc((size_t)n * DIM * 4);
    float* agg     = (float*)alloc((size_t)n * DIM * 4);

    const int nb_n = (n + 255) / 256;
    const int nb_e = (e + 255) / 256;

    zero_ints<<<nb_n, 256, 0, stream>>>(counts, n);
    zero_ints<<<nb_n, 256, 0, stream>>>(fill, n);
    count_kernel<<<nb_e, 256, 0, stream>>>(dst, counts, e);
    scan_kernel<<<1, 1024, 0, stream>>>(counts, row_ptr, n);
    invdeg_kernel<<<nb_n, 256, 0, stream>>>(counts, inv_deg, n);
    fill_csr<<<nb_e, 256, 0, stream>>>(src, dst, row_ptr, fill, col_idx, e);

    const int agg_grid  = (n + 7) / 8;        // 8 nodes per 256-thread block
    const int gemm_grid = (n + TM - 1) / TM;

    // layer 0
    aggregate_kernel<<<agg_grid, 256, 0, stream>>>(x, row_ptr, col_idx, inv_deg, agg, n);
    sage_gemm<<<gemm_grid, 256, 0, stream>>>(x, agg, W_self, W_neigh, bias, h_a, n, 1);
    // layer 1
    aggregate_kernel<<<agg_grid, 256, 0, stream>>>(h_a, row_ptr, col_idx, inv_deg, agg, n);
    sage_gemm<<<gemm_grid, 256, 0, stream>>>(h_a, agg, W_self + DIM * DIM, W_neigh + DIM * DIM,
                                             bias + DIM, h_b, n, 1);
    // layer 2
    aggregate_kernel<<<agg_grid, 256, 0, stream>>>(h_b, row_ptr, col_idx, inv_deg, agg, n);
    sage_gemm<<<gemm_grid, 256, 0, stream>>>(h_b, agg, W_self + 2 * DIM * DIM, W_neigh + 2 * DIM * DIM,
                                             bias + 2 * DIM, out, n, 0);
}

// Round 2
// 488.560 us; speedup vs baseline: 1.3177x; 1.3177x over previous
//
#include <hip/hip_runtime.h>

#define DIM 128

typedef __bf16 bf16x8 __attribute__((ext_vector_type(8)));
typedef float f32x4 __attribute__((ext_vector_type(4)));
typedef unsigned short ushort8 __attribute__((ext_vector_type(8)));

__device__ __forceinline__ unsigned short f2bf(float f) {
    union { float f; unsigned u; } x; x.f = f;
    unsigned r = x.u + 0x7FFF + ((x.u >> 16) & 1);   // RNE
    return (unsigned short)(r >> 16);
}

// ---------- setup kernels ----------

__global__ void zero_ints(int* __restrict__ p, int n) {
    int i = blockIdx.x * blockDim.x + threadIdx.x;
    if (i < n) p[i] = 0;
}

__global__ void count_kernel(const int* __restrict__ dst, int* __restrict__ counts, int E) {
    int e = blockIdx.x * blockDim.x + threadIdx.x;
    if (e < E) atomicAdd(&counts[dst[e]], 1);
}

__global__ void scan_kernel(const int* __restrict__ counts, int* __restrict__ row_ptr, int n) {
    __shared__ int sums[1024];
    int tid = threadIdx.x;
    int chunk = (n + 1023) >> 10;
    int start = tid * chunk;
    int end = min(start + chunk, n);
    int s = 0;
    for (int i = start; i < end; ++i) s += counts[i];
    sums[tid] = s;
    __syncthreads();
    for (int off = 1; off < 1024; off <<= 1) {
        int v = (tid >= off) ? sums[tid - off] : 0;
        __syncthreads();
        sums[tid] += v;
        __syncthreads();
    }
    int excl = (tid == 0) ? 0 : sums[tid - 1];
    for (int i = start; i < end; ++i) {
        row_ptr[i] = excl;
        excl += counts[i];
    }
    if (tid == 1023) row_ptr[n] = sums[1023];
}

__global__ void invdeg_kernel(const int* __restrict__ counts, float* __restrict__ inv_deg, int n) {
    int v = blockIdx.x * blockDim.x + threadIdx.x;
    if (v < n) {
        int c = counts[v];
        inv_deg[v] = 1.0f / (float)(c > 0 ? c : 1);
    }
}

__global__ void fill_csr(const int* __restrict__ src, const int* __restrict__ dst,
                         const int* __restrict__ row_ptr, int* __restrict__ fill,
                         int* __restrict__ col_idx, int E) {
    int e = blockIdx.x * blockDim.x + threadIdx.x;
    if (e < E) {
        int v = dst[e];
        int pos = row_ptr[v] + atomicAdd(&fill[v], 1);
        col_idx[pos] = src[e];
    }
}

// ---------- B pre-pack: W -> bf16 MFMA-fragment order, once per call ----------
// Dual GEMM as K=256: B_cat[k][n] = k<128 ? Ws[k][n] : Wn[k-128][n].
// Fragment: lane = n16 | quad<<4 holds 8 k-elems; addr ((ns*8+ks)*64+lane)*8.
__global__ void pack_W(const float* __restrict__ W_self, const float* __restrict__ W_neigh,
                       unsigned short* __restrict__ Bp) {
    int t = blockIdx.x * blockDim.x + threadIdx.x;   // 3*8*8*64 = 12288 threads
    if (t >= 3 * 64 * 64) return;
    int lane = t & 63;
    int g = t >> 6;            // 0..191
    int l = g >> 6;            // layer
    int r = g & 63;
    int ns = r >> 3, ks = r & 7;
    const float* Wsl = W_self + (size_t)l * DIM * DIM;
    const float* Wnl = W_neigh + (size_t)l * DIM * DIM;
    unsigned short* dst = Bp + (size_t)l * 32768 + ((size_t)(ns * 8 + ks) * 64 + lane) * 8;
    int n = ns * 16 + (lane & 15);
    int kbase = ks * 32 + (lane >> 4) * 8;
    ushort8 o;
    #pragma unroll
    for (int j = 0; j < 8; ++j) {
        int k = kbase + j;
        float v = (k < 128) ? Wsl[(size_t)k * DIM + n] : Wnl[(size_t)(k - 128) * DIM + n];
        o[j] = f2bf(v);
    }
    *(ushort8*)dst = o;
}

// ---------- aggregation (unchanged) ----------
__global__ void aggregate_kernel(const float* __restrict__ h, const int* __restrict__ row_ptr,
                                 const int* __restrict__ col_idx, const float* __restrict__ inv_deg,
                                 float* __restrict__ agg, int n) {
    int node = blockIdx.x * (blockDim.x >> 5) + (threadIdx.x >> 5);
    if (node >= n) return;
    int f = (threadIdx.x & 31) << 2;
    int b = row_ptr[node], e = row_ptr[node + 1];
    float ax = 0.f, ay = 0.f, az = 0.f, aw = 0.f;
    for (int i = b; i < e; ++i) {
        int u = col_idx[i];
        const float4 v = *(const float4*)(h + (size_t)u * DIM + f);
        ax += v.x; ay += v.y; az += v.z; aw += v.w;
    }
    float s = inv_deg[node];
    float4 o = make_float4(ax * s, ay * s, az * s, aw * s);
    *(float4*)(agg + (size_t)node * DIM + f) = o;
}

// ---------- MFMA dual GEMM: h_out = [relu]([h|agg] @ [Ws;Wn] + b) ----------
// 64 rows x 128 cols per 256-thread block; wave w owns a 16-row mtile.
// LDS = 32 KB of A fragments (bf16) -> 4 blocks/CU.
__global__ __launch_bounds__(256, 4) void sage_gemm_mfma(
    const float* __restrict__ h_in, const float* __restrict__ agg,
    const unsigned short* __restrict__ Bp, const float* __restrict__ bias,
    float* __restrict__ h_out, int n, int do_relu)
{
    __shared__ unsigned short ldsA[4 * 8 * 64 * 8];   // [mtile][kstep][lane][8]
    const int tid = threadIdx.x;
    const int row0 = blockIdx.x * 64;

    // stage A = [h | agg] rows, f32 -> bf16 fragments
    #pragma unroll
    for (int p = 0; p < 8; ++p) {
        int u = p * 256 + tid;        // 2048 units: 64 rows x 32 k-octets
        int row = u >> 5;
        int oct = u & 31;
        int k0 = oct * 8;
        int gr = row0 + row;
        float v[8];
        if (gr < n) {
            const float* srcp = (k0 < 128) ? (h_in + (size_t)gr * DIM + k0)
                                           : (agg + (size_t)gr * DIM + (k0 - 128));
            float4 f0 = *(const float4*)srcp;
            float4 f1 = *(const float4*)(srcp + 4);
            v[0] = f0.x; v[1] = f0.y; v[2] = f0.z; v[3] = f0.w;
            v[4] = f1.x; v[5] = f1.y; v[6] = f1.z; v[7] = f1.w;
        } else {
            #pragma unroll
            for (int j = 0; j < 8; ++j) v[j] = 0.f;
        }
        ushort8 o;
        #pragma unroll
        for (int j = 0; j < 8; ++j) o[j] = f2bf(v[j]);
        int mtile = row >> 4, m = row & 15;
        int kstep = k0 >> 5, quad = (k0 >> 3) & 3;
        int slot = m | (quad << 4);
        *(ushort8*)&ldsA[(((mtile * 8 + kstep) * 64) + slot) * 8] = o;
    }
    __syncthreads();

    const int w = tid >> 6;       // wave id == mtile
    const int lane = tid & 63;

    f32x4 acc[8];
    #pragma unroll
    for (int ns = 0; ns < 8; ++ns) acc[ns] = (f32x4){0.f, 0.f, 0.f, 0.f};

    const unsigned short* ldsW = &ldsA[w * 8 * 64 * 8];
    #pragma unroll
    for (int ks = 0; ks < 8; ++ks) {
        bf16x8 a = *(const bf16x8*)&ldsW[(ks * 64 + lane) * 8];
        #pragma unroll
        for (int ns = 0; ns < 8; ++ns) {
            bf16x8 b = *(const bf16x8*)&Bp[((size_t)(ns * 8 + ks) * 64 + lane) * 8];
            acc[ns] = __builtin_amdgcn_mfma_f32_16x16x32_bf16(a, b, acc[ns], 0, 0, 0);
        }
    }

    // epilogue: C/D col=lane&15, row=quad*4+reg
    const int quad = lane >> 4;
    const int col16 = lane & 15;
    #pragma unroll
    for (int ns = 0; ns < 8; ++ns) {
        int col = ns * 16 + col16;
        float bb = bias[col];
        #pragma unroll
        for (int r = 0; r < 4; ++r) {
            int gr = row0 + w * 16 + quad * 4 + r;
            if (gr < n) {
                float v = acc[ns][r] + bb;
                if (do_relu) v = fmaxf(v, 0.f);
                h_out[(size_t)gr * DIM + col] = v;
            }
        }
    }
}

// ---------- launch ----------

extern "C" void kernel_launch(void* const* d_in, const int* in_sizes, int n_in,
                              void* d_out, int out_size, void* d_ws, size_t ws_size,
                              hipStream_t stream) {
    const float* x      = (const float*)d_in[0];
    const int*   src    = (const int*)d_in[1];
    const int*   dst    = (const int*)d_in[2];
    const float* W_self = (const float*)d_in[3];
    const float* W_neigh= (const float*)d_in[4];
    const float* bias   = (const float*)d_in[5];
    float* out = (float*)d_out;

    const int n = in_sizes[0] / DIM;   // 50000
    const int e = in_sizes[1];         // 800000

    char* ws = (char*)d_ws;
    size_t off = 0;
    auto alloc = [&](size_t bytes) -> void* {
        void* p = ws + off;
        off += (bytes + 255) & ~(size_t)255;
        return p;
    };
    int*   counts  = (int*)alloc((size_t)n * 4);
    int*   fill    = (int*)alloc((size_t)n * 4);
    int*   row_ptr = (int*)alloc((size_t)(n + 1) * 4);
    int*   col_idx = (int*)alloc((size_t)e * 4);
    float* inv_deg = (float*)alloc((size_t)n * 4);
    float* h_a     = (float*)alloc((size_t)n * DIM * 4);
    float* h_b     = (float*)alloc((size_t)n * DIM * 4);
    float* agg     = (float*)alloc((size_t)n * DIM * 4);
    unsigned short* Bp = (unsigned short*)alloc((size_t)3 * 32768 * 2);

    const int nb_n = (n + 255) / 256;
    const int nb_e = (e + 255) / 256;

    zero_ints<<<nb_n, 256, 0, stream>>>(counts, n);
    zero_ints<<<nb_n, 256, 0, stream>>>(fill, n);
    count_kernel<<<nb_e, 256, 0, stream>>>(dst, counts, e);
    scan_kernel<<<1, 1024, 0, stream>>>(counts, row_ptr, n);
    invdeg_kernel<<<nb_n, 256, 0, stream>>>(counts, inv_deg, n);
    fill_csr<<<nb_e, 256, 0, stream>>>(src, dst, row_ptr, fill, col_idx, e);
    pack_W<<<48, 256, 0, stream>>>(W_self, W_neigh, Bp);

    const int agg_grid  = (n + 7) / 8;
    const int gemm_grid = (n + 63) / 64;

    // layer 0
    aggregate_kernel<<<agg_grid, 256, 0, stream>>>(x, row_ptr, col_idx, inv_deg, agg, n);
    sage_gemm_mfma<<<gemm_grid, 256, 0, stream>>>(x, agg, Bp, bias, h_a, n, 1);
    // layer 1
    aggregate_kernel<<<agg_grid, 256, 0, stream>>>(h_a, row_ptr, col_idx, inv_deg, agg, n);
    sage_gemm_mfma<<<gemm_grid, 256, 0, stream>>>(h_a, agg, Bp + 32768, bias + DIM, h_b, n, 1);
    // layer 2
    aggregate_kernel<<<agg_grid, 256, 0, stream>>>(h_b, row_ptr, col_idx, inv_deg, agg, n);
    sage_gemm_mfma<<<gemm_grid, 256, 0, stream>>>(h_b, agg, Bp + 2 * 32768, bias + 2 * DIM, out, n, 0);
}

// Round 3
// 395.852 us; speedup vs baseline: 1.6262x; 1.2342x over previous
//
#include <hip/hip_runtime.h>

#define DIM 128

typedef __bf16 bf16x8 __attribute__((ext_vector_type(8)));
typedef float f32x4 __attribute__((ext_vector_type(4)));
typedef unsigned short ushort8 __attribute__((ext_vector_type(8)));

__device__ __forceinline__ unsigned short f2bf(float f) {
    union { float f; unsigned u; } x; x.f = f;
    unsigned r = x.u + 0x7FFF + ((x.u >> 16) & 1);   // RNE
    return (unsigned short)(r >> 16);
}

// ---------- setup kernels ----------

__global__ void zero2(int* __restrict__ a, int* __restrict__ b, int n) {
    int i = blockIdx.x * blockDim.x + threadIdx.x;
    if (i < n) { a[i] = 0; b[i] = 0; }
}

__global__ void count_kernel(const int* __restrict__ dst, int* __restrict__ counts, int E) {
    int e = blockIdx.x * blockDim.x + threadIdx.x;
    if (e < E) atomicAdd(&counts[dst[e]], 1);
}

// ---- parallel exclusive scan over counts[n] -> row_ptr[n+1], fused inv_deg ----
// phase A: per-block (256-elem) sums
__global__ void scan_phase_a(const int* __restrict__ counts, int* __restrict__ block_sums, int n) {
    __shared__ int lds[256];
    int tid = threadIdx.x;
    int i = blockIdx.x * 256 + tid;
    lds[tid] = (i < n) ? counts[i] : 0;
    __syncthreads();
    #pragma unroll
    for (int off = 128; off; off >>= 1) {
        if (tid < off) lds[tid] += lds[tid + off];
        __syncthreads();
    }
    if (tid == 0) block_sums[blockIdx.x] = lds[0];
}

// phase B: single block scans block_sums[nb] (nb <= 256) -> exclusive block_off; writes row_ptr[n]
__global__ void scan_phase_b(const int* __restrict__ block_sums, int* __restrict__ block_off,
                             int* __restrict__ row_ptr, int nb, int n) {
    __shared__ int lds[256];
    int tid = threadIdx.x;
    int v = (tid < nb) ? block_sums[tid] : 0;
    lds[tid] = v;
    __syncthreads();
    #pragma unroll
    for (int off = 1; off < 256; off <<= 1) {
        int t = (tid >= off) ? lds[tid - off] : 0;
        __syncthreads();
        lds[tid] += t;
        __syncthreads();
    }
    if (tid < nb) block_off[tid] = lds[tid] - v;
    if (tid == 255) row_ptr[n] = lds[255];
}

// phase C: block-local exclusive scan + block offset -> row_ptr; fused inv_deg
__global__ void scan_phase_c(const int* __restrict__ counts, const int* __restrict__ block_off,
                             int* __restrict__ row_ptr, float* __restrict__ inv_deg, int n) {
    __shared__ int lds[256];
    int tid = threadIdx.x;
    int i = blockIdx.x * 256 + tid;
    int v = (i < n) ? counts[i] : 0;
    lds[tid] = v;
    __syncthreads();
    #pragma unroll
    for (int off = 1; off < 256; off <<= 1) {
        int t = (tid >= off) ? lds[tid - off] : 0;
        __syncthreads();
        lds[tid] += t;
        __syncthreads();
    }
    if (i < n) {
        row_ptr[i] = block_off[blockIdx.x] + lds[tid] - v;
        inv_deg[i] = 1.0f / (float)(v > 0 ? v : 1);
    }
}

__global__ void fill_csr(const int* __restrict__ src, const int* __restrict__ dst,
                         const int* __restrict__ row_ptr, int* __restrict__ fill,
                         int* __restrict__ col_idx, int E) {
    int e = blockIdx.x * blockDim.x + threadIdx.x;
    if (e < E) {
        int v = dst[e];
        int pos = row_ptr[v] + atomicAdd(&fill[v], 1);
        col_idx[pos] = src[e];
    }
}

// ---------- B pre-pack: W -> bf16 MFMA-fragment order, once per call ----------
__global__ void pack_W(const float* __restrict__ W_self, const float* __restrict__ W_neigh,
                       unsigned short* __restrict__ Bp) {
    int t = blockIdx.x * blockDim.x + threadIdx.x;
    if (t >= 3 * 64 * 64) return;
    int lane = t & 63;
    int g = t >> 6;
    int l = g >> 6;
    int r = g & 63;
    int ns = r >> 3, ks = r & 7;
    const float* Wsl = W_self + (size_t)l * DIM * DIM;
    const float* Wnl = W_neigh + (size_t)l * DIM * DIM;
    unsigned short* dstp = Bp + (size_t)l * 32768 + ((size_t)(ns * 8 + ks) * 64 + lane) * 8;
    int n = ns * 16 + (lane & 15);
    int kbase = ks * 32 + (lane >> 4) * 8;
    ushort8 o;
    #pragma unroll
    for (int j = 0; j < 8; ++j) {
        int k = kbase + j;
        float v = (k < 128) ? Wsl[(size_t)k * DIM + n] : Wnl[(size_t)(k - 128) * DIM + n];
        o[j] = f2bf(v);
    }
    *(ushort8*)dstp = o;
}

// ---------- aggregation: unroll-4 for 4x memory-level parallelism ----------
__global__ void aggregate_kernel(const float* __restrict__ h, const int* __restrict__ row_ptr,
                                 const int* __restrict__ col_idx, const float* __restrict__ inv_deg,
                                 float* __restrict__ agg, int n) {
    int node = blockIdx.x * (blockDim.x >> 5) + (threadIdx.x >> 5);
    if (node >= n) return;
    int f = (threadIdx.x & 31) << 2;
    int b = row_ptr[node], e = row_ptr[node + 1];
    float ax = 0.f, ay = 0.f, az = 0.f, aw = 0.f;
    int i = b;
    for (; i + 4 <= e; i += 4) {
        int u0 = col_idx[i];
        int u1 = col_idx[i + 1];
        int u2 = col_idx[i + 2];
        int u3 = col_idx[i + 3];
        float4 v0 = *(const float4*)(h + (size_t)u0 * DIM + f);
        float4 v1 = *(const float4*)(h + (size_t)u1 * DIM + f);
        float4 v2 = *(const float4*)(h + (size_t)u2 * DIM + f);
        float4 v3 = *(const float4*)(h + (size_t)u3 * DIM + f);
        ax += v0.x + v1.x + v2.x + v3.x;
        ay += v0.y + v1.y + v2.y + v3.y;
        az += v0.z + v1.z + v2.z + v3.z;
        aw += v0.w + v1.w + v2.w + v3.w;
    }
    for (; i < e; ++i) {
        int u = col_idx[i];
        const float4 v = *(const float4*)(h + (size_t)u * DIM + f);
        ax += v.x; ay += v.y; az += v.z; aw += v.w;
    }
    float s = inv_deg[node];
    float4 o = make_float4(ax * s, ay * s, az * s, aw * s);
    *(float4*)(agg + (size_t)node * DIM + f) = o;
}

// ---------- MFMA dual GEMM: h_out = [relu]([h|agg] @ [Ws;Wn] + b) ----------
__global__ __launch_bounds__(256, 4) void sage_gemm_mfma(
    const float* __restrict__ h_in, const float* __restrict__ agg,
    const unsigned short* __restrict__ Bp, const float* __restrict__ bias,
    float* __restrict__ h_out, int n, int do_relu)
{
    __shared__ unsigned short ldsA[4 * 8 * 64 * 8];   // [mtile][kstep][lane][8]
    const int tid = threadIdx.x;
    const int row0 = blockIdx.x * 64;

    #pragma unroll
    for (int p = 0; p < 8; ++p) {
        int u = p * 256 + tid;
        int row = u >> 5;
        int oct = u & 31;
        int k0 = oct * 8;
        int gr = row0 + row;
        float v[8];
        if (gr < n) {
            const float* srcp = (k0 < 128) ? (h_in + (size_t)gr * DIM + k0)
                                           : (agg + (size_t)gr * DIM + (k0 - 128));
            float4 f0 = *(const float4*)srcp;
            float4 f1 = *(const float4*)(srcp + 4);
            v[0] = f0.x; v[1] = f0.y; v[2] = f0.z; v[3] = f0.w;
            v[4] = f1.x; v[5] = f1.y; v[6] = f1.z; v[7] = f1.w;
        } else {
            #pragma unroll
            for (int j = 0; j < 8; ++j) v[j] = 0.f;
        }
        ushort8 o;
        #pragma unroll
        for (int j = 0; j < 8; ++j) o[j] = f2bf(v[j]);
        int mtile = row >> 4, m = row & 15;
        int kstep = k0 >> 5, quad = (k0 >> 3) & 3;
        int slot = m | (quad << 4);
        *(ushort8*)&ldsA[(((mtile * 8 + kstep) * 64) + slot) * 8] = o;
    }
    __syncthreads();

    const int w = tid >> 6;
    const int lane = tid & 63;

    f32x4 acc[8];
    #pragma unroll
    for (int ns = 0; ns < 8; ++ns) acc[ns] = (f32x4){0.f, 0.f, 0.f, 0.f};

    const unsigned short* ldsW = &ldsA[w * 8 * 64 * 8];
    #pragma unroll
    for (int ks = 0; ks < 8; ++ks) {
        bf16x8 a = *(const bf16x8*)&ldsW[(ks * 64 + lane) * 8];
        #pragma unroll
        for (int ns = 0; ns < 8; ++ns) {
            bf16x8 b = *(const bf16x8*)&Bp[((size_t)(ns * 8 + ks) * 64 + lane) * 8];
            acc[ns] = __builtin_amdgcn_mfma_f32_16x16x32_bf16(a, b, acc[ns], 0, 0, 0);
        }
    }

    const int quad = lane >> 4;
    const int col16 = lane & 15;
    #pragma unroll
    for (int ns = 0; ns < 8; ++ns) {
        int col = ns * 16 + col16;
        float bb = bias[col];
        #pragma unroll
        for (int r = 0; r < 4; ++r) {
            int gr = row0 + w * 16 + quad * 4 + r;
            if (gr < n) {
                float v = acc[ns][r] + bb;
                if (do_relu) v = fmaxf(v, 0.f);
                h_out[(size_t)gr * DIM + col] = v;
            }
        }
    }
}

// ---------- launch ----------

extern "C" void kernel_launch(void* const* d_in, const int* in_sizes, int n_in,
                              void* d_out, int out_size, void* d_ws, size_t ws_size,
                              hipStream_t stream) {
    const float* x      = (const float*)d_in[0];
    const int*   src    = (const int*)d_in[1];
    const int*   dst    = (const int*)d_in[2];
    const float* W_self = (const float*)d_in[3];
    const float* W_neigh= (const float*)d_in[4];
    const float* bias   = (const float*)d_in[5];
    float* out = (float*)d_out;

    const int n = in_sizes[0] / DIM;   // 50000
    const int e = in_sizes[1];         // 800000

    char* ws = (char*)d_ws;
    size_t off = 0;
    auto alloc = [&](size_t bytes) -> void* {
        void* p = ws + off;
        off += (bytes + 255) & ~(size_t)255;
        return p;
    };
    int*   counts     = (int*)alloc((size_t)n * 4);
    int*   fill       = (int*)alloc((size_t)n * 4);
    int*   row_ptr    = (int*)alloc((size_t)(n + 1) * 4);
    int*   col_idx    = (int*)alloc((size_t)e * 4);
    float* inv_deg    = (float*)alloc((size_t)n * 4);
    float* h_a        = (float*)alloc((size_t)n * DIM * 4);
    float* h_b        = (float*)alloc((size_t)n * DIM * 4);
    float* agg        = (float*)alloc((size_t)n * DIM * 4);
    unsigned short* Bp = (unsigned short*)alloc((size_t)3 * 32768 * 2);
    int*   block_sums = (int*)alloc(256 * 4);
    int*   block_off  = (int*)alloc(256 * 4);

    const int nb_n = (n + 255) / 256;   // 196 for n=50000 (must be <= 256)
    const int nb_e = (e + 255) / 256;

    zero2<<<nb_n, 256, 0, stream>>>(counts, fill, n);
    count_kernel<<<nb_e, 256, 0, stream>>>(dst, counts, e);
    scan_phase_a<<<nb_n, 256, 0, stream>>>(counts, block_sums, n);
    scan_phase_b<<<1, 256, 0, stream>>>(block_sums, block_off, row_ptr, nb_n, n);
    scan_phase_c<<<nb_n, 256, 0, stream>>>(counts, block_off, row_ptr, inv_deg, n);
    fill_csr<<<nb_e, 256, 0, stream>>>(src, dst, row_ptr, fill, col_idx, e);
    pack_W<<<48, 256, 0, stream>>>(W_self, W_neigh, Bp);

    const int agg_grid  = (n + 7) / 8;
    const int gemm_grid = (n + 63) / 64;

    // layer 0
    aggregate_kernel<<<agg_grid, 256, 0, stream>>>(x, row_ptr, col_idx, inv_deg, agg, n);
    sage_gemm_mfma<<<gemm_grid, 256, 0, stream>>>(x, agg, Bp, bias, h_a, n, 1);
    // layer 1
    aggregate_kernel<<<agg_grid, 256, 0, stream>>>(h_a, row_ptr, col_idx, inv_deg, agg, n);
    sage_gemm_mfma<<<gemm_grid, 256, 0, stream>>>(h_a, agg, Bp + 32768, bias + DIM, h_b, n, 1);
    // layer 2
    aggregate_kernel<<<agg_grid, 256, 0, stream>>>(h_b, row_ptr, col_idx, inv_deg, agg, n);
    sage_gemm_mfma<<<gemm_grid, 256, 0, stream>>>(h_b, agg, Bp + 2 * 32768, bias + 2 * DIM, out, n, 0);
}

// Round 4
// 331.926 us; speedup vs baseline: 1.9394x; 1.1926x over previous
//
#include <hip/hip_runtime.h>

#define DIM 128

typedef __bf16 bf16x8 __attribute__((ext_vector_type(8)));
typedef float f32x4 __attribute__((ext_vector_type(4)));
typedef unsigned short ushort8 __attribute__((ext_vector_type(8)));
typedef unsigned short us4 __attribute__((ext_vector_type(4)));

__device__ __forceinline__ unsigned short f2bf(float f) {
    union { float f; unsigned u; } x; x.f = f;
    unsigned r = x.u + 0x7FFF + ((x.u >> 16) & 1);   // RNE
    return (unsigned short)(r >> 16);
}

__device__ __forceinline__ float bf2f(unsigned short u) {
    union { unsigned u; float f; } x; x.u = ((unsigned)u) << 16;
    return x.f;
}

// ---------- setup kernels ----------

__global__ void zero2(int* __restrict__ a, int* __restrict__ b, int n) {
    int i = blockIdx.x * blockDim.x + threadIdx.x;
    if (i < n) { a[i] = 0; b[i] = 0; }
}

__global__ void count_kernel(const int* __restrict__ dst, int* __restrict__ counts, int E) {
    int e = blockIdx.x * blockDim.x + threadIdx.x;
    if (e < E) atomicAdd(&counts[dst[e]], 1);
}

// ---- parallel exclusive scan over counts[n] -> row_ptr[n+1], fused inv_deg ----
__global__ void scan_phase_a(const int* __restrict__ counts, int* __restrict__ block_sums, int n) {
    __shared__ int lds[256];
    int tid = threadIdx.x;
    int i = blockIdx.x * 256 + tid;
    lds[tid] = (i < n) ? counts[i] : 0;
    __syncthreads();
    #pragma unroll
    for (int off = 128; off; off >>= 1) {
        if (tid < off) lds[tid] += lds[tid + off];
        __syncthreads();
    }
    if (tid == 0) block_sums[blockIdx.x] = lds[0];
}

__global__ void scan_phase_b(const int* __restrict__ block_sums, int* __restrict__ block_off,
                             int* __restrict__ row_ptr, int nb, int n) {
    __shared__ int lds[256];
    int tid = threadIdx.x;
    int v = (tid < nb) ? block_sums[tid] : 0;
    lds[tid] = v;
    __syncthreads();
    #pragma unroll
    for (int off = 1; off < 256; off <<= 1) {
        int t = (tid >= off) ? lds[tid - off] : 0;
        __syncthreads();
        lds[tid] += t;
        __syncthreads();
    }
    if (tid < nb) block_off[tid] = lds[tid] - v;
    if (tid == 255) row_ptr[n] = lds[255];
}

__global__ void scan_phase_c(const int* __restrict__ counts, const int* __restrict__ block_off,
                             int* __restrict__ row_ptr, float* __restrict__ inv_deg, int n) {
    __shared__ int lds[256];
    int tid = threadIdx.x;
    int i = blockIdx.x * 256 + tid;
    int v = (i < n) ? counts[i] : 0;
    lds[tid] = v;
    __syncthreads();
    #pragma unroll
    for (int off = 1; off < 256; off <<= 1) {
        int t = (tid >= off) ? lds[tid - off] : 0;
        __syncthreads();
        lds[tid] += t;
        __syncthreads();
    }
    if (i < n) {
        row_ptr[i] = block_off[blockIdx.x] + lds[tid] - v;
        inv_deg[i] = 1.0f / (float)(v > 0 ? v : 1);
    }
}

__global__ void fill_csr(const int* __restrict__ src, const int* __restrict__ dst,
                         const int* __restrict__ row_ptr, int* __restrict__ fill,
                         int* __restrict__ col_idx, int E) {
    int e = blockIdx.x * blockDim.x + threadIdx.x;
    if (e < E) {
        int v = dst[e];
        int pos = row_ptr[v] + atomicAdd(&fill[v], 1);
        col_idx[pos] = src[e];
    }
}

// ---------- x f32 -> bf16 (once per call) ----------
__global__ void conv_f32_bf(const float* __restrict__ x, unsigned short* __restrict__ xb, int n8) {
    int i = blockIdx.x * blockDim.x + threadIdx.x;
    if (i >= n8) return;
    const float4* p = (const float4*)(x + (size_t)i * 8);
    float4 a = p[0], b = p[1];
    ushort8 o = {f2bf(a.x), f2bf(a.y), f2bf(a.z), f2bf(a.w),
                 f2bf(b.x), f2bf(b.y), f2bf(b.z), f2bf(b.w)};
    *(ushort8*)(xb + (size_t)i * 8) = o;
}

// ---------- B pre-pack: W -> bf16 MFMA-fragment order ----------
__global__ void pack_W(const float* __restrict__ W_self, const float* __restrict__ W_neigh,
                       unsigned short* __restrict__ Bp) {
    int t = blockIdx.x * blockDim.x + threadIdx.x;
    if (t >= 3 * 64 * 64) return;
    int lane = t & 63;
    int g = t >> 6;
    int l = g >> 6;
    int r = g & 63;
    int ns = r >> 3, ks = r & 7;
    const float* Wsl = W_self + (size_t)l * DIM * DIM;
    const float* Wnl = W_neigh + (size_t)l * DIM * DIM;
    unsigned short* dstp = Bp + (size_t)l * 32768 + ((size_t)(ns * 8 + ks) * 64 + lane) * 8;
    int n = ns * 16 + (lane & 15);
    int kbase = ks * 32 + (lane >> 4) * 8;
    ushort8 o;
    #pragma unroll
    for (int j = 0; j < 8; ++j) {
        int k = kbase + j;
        float v = (k < 128) ? Wsl[(size_t)k * DIM + n] : Wnl[(size_t)(k - 128) * DIM + n];
        o[j] = f2bf(v);
    }
    *(ushort8*)dstp = o;
}

// ---------- aggregation over bf16 rows: 256B/row, 32 lanes x 8B ----------
__global__ void aggregate_bf(const unsigned short* __restrict__ h, const int* __restrict__ row_ptr,
                             const int* __restrict__ col_idx, const float* __restrict__ inv_deg,
                             unsigned short* __restrict__ agg, int n) {
    int node = blockIdx.x * (blockDim.x >> 5) + (threadIdx.x >> 5);
    if (node >= n) return;
    int f = (threadIdx.x & 31) << 2;
    int b = row_ptr[node], e = row_ptr[node + 1];
    float ax = 0.f, ay = 0.f, az = 0.f, aw = 0.f;
    int i = b;
    for (; i + 4 <= e; i += 4) {
        int u0 = col_idx[i];
        int u1 = col_idx[i + 1];
        int u2 = col_idx[i + 2];
        int u3 = col_idx[i + 3];
        us4 v0 = *(const us4*)(h + (size_t)u0 * DIM + f);
        us4 v1 = *(const us4*)(h + (size_t)u1 * DIM + f);
        us4 v2 = *(const us4*)(h + (size_t)u2 * DIM + f);
        us4 v3 = *(const us4*)(h + (size_t)u3 * DIM + f);
        ax += bf2f(v0[0]) + bf2f(v1[0]) + bf2f(v2[0]) + bf2f(v3[0]);
        ay += bf2f(v0[1]) + bf2f(v1[1]) + bf2f(v2[1]) + bf2f(v3[1]);
        az += bf2f(v0[2]) + bf2f(v1[2]) + bf2f(v2[2]) + bf2f(v3[2]);
        aw += bf2f(v0[3]) + bf2f(v1[3]) + bf2f(v2[3]) + bf2f(v3[3]);
    }
    for (; i < e; ++i) {
        int u = col_idx[i];
        us4 v = *(const us4*)(h + (size_t)u * DIM + f);
        ax += bf2f(v[0]); ay += bf2f(v[1]); az += bf2f(v[2]); aw += bf2f(v[3]);
    }
    float s = inv_deg[node];
    us4 o = {f2bf(ax * s), f2bf(ay * s), f2bf(az * s), f2bf(aw * s)};
    *(us4*)(agg + (size_t)node * DIM + f) = o;
}

// ---------- MFMA dual GEMM: out = [relu]([h|agg] @ [Ws;Wn] + b) ----------
// A is bf16 already: staging = pure 16B copies. out_bf != null -> bf16 out, else f32.
__global__ __launch_bounds__(256, 4) void sage_gemm_mfma(
    const unsigned short* __restrict__ hb, const unsigned short* __restrict__ aggb,
    const unsigned short* __restrict__ Bp, const float* __restrict__ bias,
    unsigned short* __restrict__ out_bf, float* __restrict__ out_f32,
    int n, int do_relu)
{
    __shared__ unsigned short ldsA[4 * 8 * 64 * 8];   // [mtile][kstep][slot][8]
    const int tid = threadIdx.x;
    const int row0 = blockIdx.x * 64;

    #pragma unroll
    for (int p = 0; p < 8; ++p) {
        int u = p * 256 + tid;            // 2048 units: 64 rows x 32 k-octets
        int row = u >> 5;
        int oct = u & 31;
        int gr = row0 + row;
        ushort8 o = {0, 0, 0, 0, 0, 0, 0, 0};
        if (gr < n) {
            const unsigned short* s = (oct < 16) ? (hb + (size_t)gr * DIM + oct * 8)
                                                 : (aggb + (size_t)gr * DIM + (oct - 16) * 8);
            o = *(const ushort8*)s;
        }
        int mtile = row >> 4, m = row & 15;
        int kstep = oct >> 2, quad = oct & 3;
        int slot = m | (quad << 4);
        *(ushort8*)&ldsA[(((mtile * 8 + kstep) * 64) + slot) * 8] = o;
    }
    __syncthreads();

    const int w = tid >> 6;
    const int lane = tid & 63;

    f32x4 acc[8];
    #pragma unroll
    for (int ns = 0; ns < 8; ++ns) acc[ns] = (f32x4){0.f, 0.f, 0.f, 0.f};

    const unsigned short* ldsW = &ldsA[w * 8 * 64 * 8];
    #pragma unroll
    for (int ks = 0; ks < 8; ++ks) {
        bf16x8 a = *(const bf16x8*)&ldsW[(ks * 64 + lane) * 8];
        #pragma unroll
        for (int ns = 0; ns < 8; ++ns) {
            bf16x8 b = *(const bf16x8*)&Bp[((size_t)(ns * 8 + ks) * 64 + lane) * 8];
            acc[ns] = __builtin_amdgcn_mfma_f32_16x16x32_bf16(a, b, acc[ns], 0, 0, 0);
        }
    }

    const int quad = lane >> 4;
    const int col16 = lane & 15;
    #pragma unroll
    for (int ns = 0; ns < 8; ++ns) {
        int col = ns * 16 + col16;
        float bb = bias[col];
        #pragma unroll
        for (int r = 0; r < 4; ++r) {
            int gr = row0 + w * 16 + quad * 4 + r;
            if (gr < n) {
                float v = acc[ns][r] + bb;
                if (do_relu) v = fmaxf(v, 0.f);
                if (out_bf) out_bf[(size_t)gr * DIM + col] = f2bf(v);
                else        out_f32[(size_t)gr * DIM + col] = v;
            }
        }
    }
}

// ---------- launch ----------

extern "C" void kernel_launch(void* const* d_in, const int* in_sizes, int n_in,
                              void* d_out, int out_size, void* d_ws, size_t ws_size,
                              hipStream_t stream) {
    const float* x      = (const float*)d_in[0];
    const int*   src    = (const int*)d_in[1];
    const int*   dst    = (const int*)d_in[2];
    const float* W_self = (const float*)d_in[3];
    const float* W_neigh= (const float*)d_in[4];
    const float* bias   = (const float*)d_in[5];
    float* out = (float*)d_out;

    const int n = in_sizes[0] / DIM;   // 50000
    const int e = in_sizes[1];         // 800000

    char* ws = (char*)d_ws;
    size_t off = 0;
    auto alloc = [&](size_t bytes) -> void* {
        void* p = ws + off;
        off += (bytes + 255) & ~(size_t)255;
        return p;
    };
    int*   counts     = (int*)alloc((size_t)n * 4);
    int*   fill       = (int*)alloc((size_t)n * 4);
    int*   row_ptr    = (int*)alloc((size_t)(n + 1) * 4);
    int*   col_idx    = (int*)alloc((size_t)e * 4);
    float* inv_deg    = (float*)alloc((size_t)n * 4);
    unsigned short* x_bf  = (unsigned short*)alloc((size_t)n * DIM * 2);
    unsigned short* h_a   = (unsigned short*)alloc((size_t)n * DIM * 2);
    unsigned short* h_b   = (unsigned short*)alloc((size_t)n * DIM * 2);
    unsigned short* aggb  = (unsigned short*)alloc((size_t)n * DIM * 2);
    unsigned short* Bp    = (unsigned short*)alloc((size_t)3 * 32768 * 2);
    int*   block_sums = (int*)alloc(256 * 4);
    int*   block_off  = (int*)alloc(256 * 4);

    const int nb_n = (n + 255) / 256;   // 196 (<= 256)
    const int nb_e = (e + 255) / 256;
    const int n8   = n * DIM / 8;       // 800000

    zero2<<<nb_n, 256, 0, stream>>>(counts, fill, n);
    count_kernel<<<nb_e, 256, 0, stream>>>(dst, counts, e);
    scan_phase_a<<<nb_n, 256, 0, stream>>>(counts, block_sums, n);
    scan_phase_b<<<1, 256, 0, stream>>>(block_sums, block_off, row_ptr, nb_n, n);
    scan_phase_c<<<nb_n, 256, 0, stream>>>(counts, block_off, row_ptr, inv_deg, n);
    fill_csr<<<nb_e, 256, 0, stream>>>(src, dst, row_ptr, fill, col_idx, e);
    conv_f32_bf<<<(n8 + 255) / 256, 256, 0, stream>>>(x, x_bf, n8);
    pack_W<<<48, 256, 0, stream>>>(W_self, W_neigh, Bp);

    const int agg_grid  = (n + 7) / 8;
    const int gemm_grid = (n + 63) / 64;

    // layer 0
    aggregate_bf<<<agg_grid, 256, 0, stream>>>(x_bf, row_ptr, col_idx, inv_deg, aggb, n);
    sage_gemm_mfma<<<gemm_grid, 256, 0, stream>>>(x_bf, aggb, Bp, bias, h_a, nullptr, n, 1);
    // layer 1
    aggregate_bf<<<agg_grid, 256, 0, stream>>>(h_a, row_ptr, col_idx, inv_deg, aggb, n);
    sage_gemm_mfma<<<gemm_grid, 256, 0, stream>>>(h_a, aggb, Bp + 32768, bias + DIM, h_b, nullptr, n, 1);
    // layer 2
    aggregate_bf<<<agg_grid, 256, 0, stream>>>(h_b, row_ptr, col_idx, inv_deg, aggb, n);
    sage_gemm_mfma<<<gemm_grid, 256, 0, stream>>>(h_b, aggb, Bp + 2 * 32768, bias + 2 * DIM,
                                                  nullptr, out, n, 0);
}

// Round 5
// 311.695 us; speedup vs baseline: 2.0653x; 1.0649x over previous
//
#include <hip/hip_runtime.h>

#define DIM 128

typedef __bf16 bf16x8 __attribute__((ext_vector_type(8)));
typedef float f32x4 __attribute__((ext_vector_type(4)));
typedef unsigned short ushort8 __attribute__((ext_vector_type(8)));
typedef unsigned short us4 __attribute__((ext_vector_type(4)));

__device__ __forceinline__ unsigned short f2bf(float f) {
    union { float f; unsigned u; } x; x.f = f;
    unsigned r = x.u + 0x7FFF + ((x.u >> 16) & 1);   // RNE
    return (unsigned short)(r >> 16);
}

__device__ __forceinline__ float bf2f(unsigned short u) {
    union { unsigned u; float f; } x; x.u = ((unsigned)u) << 16;
    return x.f;
}

// ---------- setup kernels ----------

__global__ void zero1(int* __restrict__ a, int n) {
    int i = blockIdx.x * blockDim.x + threadIdx.x;
    if (i < n) a[i] = 0;
}

// count + per-edge position in one atomic pass
__global__ void count_pos(const int* __restrict__ dst, int* __restrict__ counts,
                          int* __restrict__ pos_in_node, int E) {
    int e = blockIdx.x * blockDim.x + threadIdx.x;
    if (e < E) pos_in_node[e] = atomicAdd(&counts[dst[e]], 1);
}

// ---- parallel exclusive scan over counts[n] -> row_ptr[n+1], fused inv_deg ----
__global__ void scan_phase_a(const int* __restrict__ counts, int* __restrict__ block_sums, int n) {
    __shared__ int lds[256];
    int tid = threadIdx.x;
    int i = blockIdx.x * 256 + tid;
    lds[tid] = (i < n) ? counts[i] : 0;
    __syncthreads();
    #pragma unroll
    for (int off = 128; off; off >>= 1) {
        if (tid < off) lds[tid] += lds[tid + off];
        __syncthreads();
    }
    if (tid == 0) block_sums[blockIdx.x] = lds[0];
}

__global__ void scan_phase_b(const int* __restrict__ block_sums, int* __restrict__ block_off,
                             int* __restrict__ row_ptr, int nb, int n) {
    __shared__ int lds[256];
    int tid = threadIdx.x;
    int v = (tid < nb) ? block_sums[tid] : 0;
    lds[tid] = v;
    __syncthreads();
    #pragma unroll
    for (int off = 1; off < 256; off <<= 1) {
        int t = (tid >= off) ? lds[tid - off] : 0;
        __syncthreads();
        lds[tid] += t;
        __syncthreads();
    }
    if (tid < nb) block_off[tid] = lds[tid] - v;
    if (tid == 255) row_ptr[n] = lds[255];
}

__global__ void scan_phase_c(const int* __restrict__ counts, const int* __restrict__ block_off,
                             int* __restrict__ row_ptr, float* __restrict__ inv_deg, int n) {
    __shared__ int lds[256];
    int tid = threadIdx.x;
    int i = blockIdx.x * 256 + tid;
    int v = (i < n) ? counts[i] : 0;
    lds[tid] = v;
    __syncthreads();
    #pragma unroll
    for (int off = 1; off < 256; off <<= 1) {
        int t = (tid >= off) ? lds[tid - off] : 0;
        __syncthreads();
        lds[tid] += t;
        __syncthreads();
    }
    if (i < n) {
        row_ptr[i] = block_off[blockIdx.x] + lds[tid] - v;
        inv_deg[i] = 1.0f / (float)(v > 0 ? v : 1);
    }
}

// atomic-free scatter: col_idx[row_ptr[dst] + pos] = src  (nt store: don't thrash L2)
__global__ void fill_scatter(const int* __restrict__ src, const int* __restrict__ dst,
                             const int* __restrict__ row_ptr, const int* __restrict__ pos_in_node,
                             int* __restrict__ col_idx, int E) {
    int e = blockIdx.x * blockDim.x + threadIdx.x;
    if (e < E) {
        int pos = row_ptr[dst[e]] + pos_in_node[e];
        __builtin_nontemporal_store(src[e], &col_idx[pos]);
    }
}

// ---------- x f32 -> bf16 (once per call) ----------
__global__ void conv_f32_bf(const float* __restrict__ x, unsigned short* __restrict__ xb, int n8) {
    int i = blockIdx.x * blockDim.x + threadIdx.x;
    if (i >= n8) return;
    const float4* p = (const float4*)(x + (size_t)i * 8);
    float4 a = p[0], b = p[1];
    ushort8 o = {f2bf(a.x), f2bf(a.y), f2bf(a.z), f2bf(a.w),
                 f2bf(b.x), f2bf(b.y), f2bf(b.z), f2bf(b.w)};
    *(ushort8*)(xb + (size_t)i * 8) = o;
}

// ---------- B pre-pack: W -> bf16 MFMA-fragment order ----------
__global__ void pack_W(const float* __restrict__ W_self, const float* __restrict__ W_neigh,
                       unsigned short* __restrict__ Bp) {
    int t = blockIdx.x * blockDim.x + threadIdx.x;
    if (t >= 3 * 64 * 64) return;
    int lane = t & 63;
    int g = t >> 6;
    int l = g >> 6;
    int r = g & 63;
    int ns = r >> 3, ks = r & 7;
    const float* Wsl = W_self + (size_t)l * DIM * DIM;
    const float* Wnl = W_neigh + (size_t)l * DIM * DIM;
    unsigned short* dstp = Bp + (size_t)l * 32768 + ((size_t)(ns * 8 + ks) * 64 + lane) * 8;
    int n = ns * 16 + (lane & 15);
    int kbase = ks * 32 + (lane >> 4) * 8;
    ushort8 o;
    #pragma unroll
    for (int j = 0; j < 8; ++j) {
        int k = kbase + j;
        float v = (k < 128) ? Wsl[(size_t)k * DIM + n] : Wnl[(size_t)(k - 128) * DIM + n];
        o[j] = f2bf(v);
    }
    *(ushort8*)dstp = o;
}

// ---------- aggregation over bf16 rows: 256B/row, 32 lanes x 8B ----------
__global__ void aggregate_bf(const unsigned short* __restrict__ h, const int* __restrict__ row_ptr,
                             const int* __restrict__ col_idx, const float* __restrict__ inv_deg,
                             unsigned short* __restrict__ agg, int n) {
    int node = blockIdx.x * (blockDim.x >> 5) + (threadIdx.x >> 5);
    if (node >= n) return;
    int f = (threadIdx.x & 31) << 2;
    int b = row_ptr[node], e = row_ptr[node + 1];
    float ax = 0.f, ay = 0.f, az = 0.f, aw = 0.f;
    int i = b;
    for (; i + 4 <= e; i += 4) {
        int u0 = col_idx[i];
        int u1 = col_idx[i + 1];
        int u2 = col_idx[i + 2];
        int u3 = col_idx[i + 3];
        us4 v0 = *(const us4*)(h + (size_t)u0 * DIM + f);
        us4 v1 = *(const us4*)(h + (size_t)u1 * DIM + f);
        us4 v2 = *(const us4*)(h + (size_t)u2 * DIM + f);
        us4 v3 = *(const us4*)(h + (size_t)u3 * DIM + f);
        ax += bf2f(v0[0]) + bf2f(v1[0]) + bf2f(v2[0]) + bf2f(v3[0]);
        ay += bf2f(v0[1]) + bf2f(v1[1]) + bf2f(v2[1]) + bf2f(v3[1]);
        az += bf2f(v0[2]) + bf2f(v1[2]) + bf2f(v2[2]) + bf2f(v3[2]);
        aw += bf2f(v0[3]) + bf2f(v1[3]) + bf2f(v2[3]) + bf2f(v3[3]);
    }
    for (; i < e; ++i) {
        int u = col_idx[i];
        us4 v = *(const us4*)(h + (size_t)u * DIM + f);
        ax += bf2f(v[0]); ay += bf2f(v[1]); az += bf2f(v[2]); aw += bf2f(v[3]);
    }
    float s = inv_deg[node];
    us4 o = {f2bf(ax * s), f2bf(ay * s), f2bf(az * s), f2bf(aw * s)};
    *(us4*)(agg + (size_t)node * DIM + f) = o;
}

// ---------- MFMA dual GEMM: out = [relu]([h|agg] @ [Ws;Wn] + b) ----------
__global__ __launch_bounds__(256, 4) void sage_gemm_mfma(
    const unsigned short* __restrict__ hb, const unsigned short* __restrict__ aggb,
    const unsigned short* __restrict__ Bp, const float* __restrict__ bias,
    unsigned short* __restrict__ out_bf, float* __restrict__ out_f32,
    int n, int do_relu)
{
    __shared__ unsigned short ldsA[4 * 8 * 64 * 8];   // [mtile][kstep][slot][8]
    const int tid = threadIdx.x;
    const int row0 = blockIdx.x * 64;

    #pragma unroll
    for (int p = 0; p < 8; ++p) {
        int u = p * 256 + tid;            // 2048 units: 64 rows x 32 k-octets
        int row = u >> 5;
        int oct = u & 31;
        int gr = row0 + row;
        ushort8 o = {0, 0, 0, 0, 0, 0, 0, 0};
        if (gr < n) {
            const unsigned short* s = (oct < 16) ? (hb + (size_t)gr * DIM + oct * 8)
                                                 : (aggb + (size_t)gr * DIM + (oct - 16) * 8);
            o = *(const ushort8*)s;
        }
        int mtile = row >> 4, m = row & 15;
        int kstep = oct >> 2, quad = oct & 3;
        int slot = m | (quad << 4);
        *(ushort8*)&ldsA[(((mtile * 8 + kstep) * 64) + slot) * 8] = o;
    }
    __syncthreads();

    const int w = tid >> 6;
    const int lane = tid & 63;

    f32x4 acc[8];
    #pragma unroll
    for (int ns = 0; ns < 8; ++ns) acc[ns] = (f32x4){0.f, 0.f, 0.f, 0.f};

    const unsigned short* ldsW = &ldsA[w * 8 * 64 * 8];
    #pragma unroll
    for (int ks = 0; ks < 8; ++ks) {
        bf16x8 a = *(const bf16x8*)&ldsW[(ks * 64 + lane) * 8];
        #pragma unroll
        for (int ns = 0; ns < 8; ++ns) {
            bf16x8 b = *(const bf16x8*)&Bp[((size_t)(ns * 8 + ks) * 64 + lane) * 8];
            acc[ns] = __builtin_amdgcn_mfma_f32_16x16x32_bf16(a, b, acc[ns], 0, 0, 0);
        }
    }

    const int quad = lane >> 4;
    const int col16 = lane & 15;
    #pragma unroll
    for (int ns = 0; ns < 8; ++ns) {
        int col = ns * 16 + col16;
        float bb = bias[col];
        #pragma unroll
        for (int r = 0; r < 4; ++r) {
            int gr = row0 + w * 16 + quad * 4 + r;
            if (gr < n) {
                float v = acc[ns][r] + bb;
                if (do_relu) v = fmaxf(v, 0.f);
                if (out_bf) out_bf[(size_t)gr * DIM + col] = f2bf(v);
                else        out_f32[(size_t)gr * DIM + col] = v;
            }
        }
    }
}

// ---------- launch ----------

extern "C" void kernel_launch(void* const* d_in, const int* in_sizes, int n_in,
                              void* d_out, int out_size, void* d_ws, size_t ws_size,
                              hipStream_t stream) {
    const float* x      = (const float*)d_in[0];
    const int*   src    = (const int*)d_in[1];
    const int*   dst    = (const int*)d_in[2];
    const float* W_self = (const float*)d_in[3];
    const float* W_neigh= (const float*)d_in[4];
    const float* bias   = (const float*)d_in[5];
    float* out = (float*)d_out;

    const int n = in_sizes[0] / DIM;   // 50000
    const int e = in_sizes[1];         // 800000

    char* ws = (char*)d_ws;
    size_t off = 0;
    auto alloc = [&](size_t bytes) -> void* {
        void* p = ws + off;
        off += (bytes + 255) & ~(size_t)255;
        return p;
    };
    int*   counts      = (int*)alloc((size_t)n * 4);
    int*   row_ptr     = (int*)alloc((size_t)(n + 1) * 4);
    int*   col_idx     = (int*)alloc((size_t)e * 4);
    int*   pos_in_node = (int*)alloc((size_t)e * 4);
    float* inv_deg     = (float*)alloc((size_t)n * 4);
    unsigned short* x_bf  = (unsigned short*)alloc((size_t)n * DIM * 2);
    unsigned short* h_a   = (unsigned short*)alloc((size_t)n * DIM * 2);
    unsigned short* h_b   = (unsigned short*)alloc((size_t)n * DIM * 2);
    unsigned short* aggb  = (unsigned short*)alloc((size_t)n * DIM * 2);
    unsigned short* Bp    = (unsigned short*)alloc((size_t)3 * 32768 * 2);
    int*   block_sums  = (int*)alloc(256 * 4);
    int*   block_off   = (int*)alloc(256 * 4);

    const int nb_n = (n + 255) / 256;   // 196 (<= 256)
    const int nb_e = (e + 255) / 256;
    const int n8   = n * DIM / 8;       // 800000

    zero1<<<nb_n, 256, 0, stream>>>(counts, n);
    count_pos<<<nb_e, 256, 0, stream>>>(dst, counts, pos_in_node, e);
    scan_phase_a<<<nb_n, 256, 0, stream>>>(counts, block_sums, n);
    scan_phase_b<<<1, 256, 0, stream>>>(block_sums, block_off, row_ptr, nb_n, n);
    scan_phase_c<<<nb_n, 256, 0, stream>>>(counts, block_off, row_ptr, inv_deg, n);
    fill_scatter<<<nb_e, 256, 0, stream>>>(src, dst, row_ptr, pos_in_node, col_idx, e);
    conv_f32_bf<<<(n8 + 255) / 256, 256, 0, stream>>>(x, x_bf, n8);
    pack_W<<<48, 256, 0, stream>>>(W_self, W_neigh, Bp);

    const int agg_grid  = (n + 7) / 8;
    const int gemm_grid = (n + 63) / 64;

    // layer 0
    aggregate_bf<<<agg_grid, 256, 0, stream>>>(x_bf, row_ptr, col_idx, inv_deg, aggb, n);
    sage_gemm_mfma<<<gemm_grid, 256, 0, stream>>>(x_bf, aggb, Bp, bias, h_a, nullptr, n, 1);
    // layer 1
    aggregate_bf<<<agg_grid, 256, 0, stream>>>(h_a, row_ptr, col_idx, inv_deg, aggb, n);
    sage_gemm_mfma<<<gemm_grid, 256, 0, stream>>>(h_a, aggb, Bp + 32768, bias + DIM, h_b, nullptr, n, 1);
    // layer 2
    aggregate_bf<<<agg_grid, 256, 0, stream>>>(h_b, row_ptr, col_idx, inv_deg, aggb, n);
    sage_gemm_mfma<<<gemm_grid, 256, 0, stream>>>(h_b, aggb, Bp + 2 * 32768, bias + 2 * DIM,
                                                  nullptr, out, n, 0);
}